// Round 6
// baseline (488.022 us; speedup 1.0000x reference)
//
#include <hip/hip_runtime.h>
#include <stdint.h>

#define HB 8
#define HL 128
#define HV 50257
#define HE 768
#define HM 400
#define HMT 800
#define HBL (HB*HL)
#define NTILES 393   // ceil(HV/128)
#define ELD 50272    // padded bf16-exp leading dim (mult of 16)

typedef __attribute__((ext_vector_type(4))) float f32x4;
typedef __attribute__((ext_vector_type(8))) short bf16x8;
typedef unsigned short u16;

struct u16x4 { u16 x, y, z, w; };

__device__ __forceinline__ u16 f2bf(float x){
  union { float f; uint32_t u; } v; v.f = x;
  uint32_t r = v.u + 0x7fffu + ((v.u >> 16) & 1u);
  return (u16)(r >> 16);
}
__device__ __forceinline__ float bf2f(u16 b){
  union { uint32_t u; float f; } v; v.u = ((uint32_t)b) << 16;
  return v.f;
}
__device__ __forceinline__ void glds(const u16* g, const u16* l){
  __builtin_amdgcn_global_load_lds(
      (const __attribute__((address_space(1))) void*)g,
      (__attribute__((address_space(3))) void*)l, 16, 0, 0);
}

// ---- fused preprocessing: hid, rel, Wr1, Wt, wcat, vmm, wte cvt ------------
__global__ __launch_bounds__(256) void prep_k(const float* __restrict__ hs,
    const float* __restrict__ rel, const float* __restrict__ Wr1src,
    const float* __restrict__ Wtsrc, const float* __restrict__ Ws1,
    const float* __restrict__ Wn1, const int* __restrict__ vmap,
    const int* __restrict__ mmask, const float* __restrict__ wte,
    u16* __restrict__ hid_b, u16* __restrict__ rel_b,
    u16* __restrict__ wr1, u16* __restrict__ wt_b, u16* __restrict__ wcat,
    int* __restrict__ vmm, u16* __restrict__ wte_b){
  const int b = blockIdx.x, t = threadIdx.x;
  if (b >= 5456) {
    long i = (long)(b-5456)*256 + t;
    if (i < (long)HV*HE/4) {
      float4 x = ((const float4*)wte)[i];
      u16x4 y; y.x=f2bf(x.x); y.y=f2bf(x.y); y.z=f2bf(x.z); y.w=f2bf(x.w);
      ((u16x4*)wte_b)[i] = y;
    }
    return;
  }
  if (b < 768) {
    int i = b*256 + t;
    float4 x = ((const float4*)hs)[i];
    u16x4 y; y.x=f2bf(x.x); y.y=f2bf(x.y); y.z=f2bf(x.z); y.w=f2bf(x.w);
    ((u16x4*)hid_b)[i] = y;
  } else if (b < 798) {
    int i = (b-768)*256 + t;
    float4 x = ((const float4*)rel)[i];
    u16x4 y; y.x=f2bf(x.x); y.y=f2bf(x.y); y.z=f2bf(x.z); y.w=f2bf(x.w);
    ((u16x4*)rel_b)[i] = y;
  } else if (b < 1374) {
    int i = (b-798)*256 + t;
    float4 x = ((const float4*)Wr1src)[i];
    u16x4 y; y.x=f2bf(x.x); y.y=f2bf(x.y); y.z=f2bf(x.z); y.w=f2bf(x.w);
    ((u16x4*)wr1)[i] = y;
  } else if (b < 3102) {
    int i = (b-1374)*256 + t;
    float4 x = ((const float4*)Wtsrc)[i];
    u16x4 y; y.x=f2bf(x.x); y.y=f2bf(x.y); y.z=f2bf(x.z); y.w=f2bf(x.w);
    ((u16x4*)wt_b)[i] = y;
  } else if (b < 5406) {
    int i = (b-3102)*256 + t;
    int e = i / HE, k = i - e*HE;
    wcat[(long)e*(2*HE) + k]      = f2bf(Ws1[i]);
    wcat[(long)e*(2*HE) + HE + k] = f2bf(Wn1[i]);
  } else {
    int base = (b-5406)*1024 + t*4;
    #pragma unroll
    for (int i = 0; i < 4; ++i) {
      int c = base + i;
      if (c < HV) vmm[c] = mmask[c] ? vmap[c] : -1;
    }
  }
}

// ---- fused GCN scatter + anode build (per batch x 16-col chunk) ------------
__global__ __launch_bounds__(256) void gcn_scatter_k(const float* __restrict__ wte,
    const float* __restrict__ rel, const int* __restrict__ cids,
    const int* __restrict__ rids, const int* __restrict__ head,
    const int* __restrict__ tail, u16* __restrict__ An){
  const int ch = blockIdx.x % 48;
  const int b  = blockIdx.x / 48;
  const int e0 = ch * 16;
  __shared__ float cw[HM][17];
  __shared__ float upd[HM][17];
  __shared__ float relc[40][17];
  __shared__ float cnt[HM];
  const int tid = threadIdx.x;

  for (int idx = tid; idx < HM*16; idx += 256) {
    int m = idx >> 4, e = idx & 15;
    cw[m][e] = wte[(long)cids[b*HM+m]*HE + e0 + e];
    upd[m][e] = 0.f;
  }
  for (int idx = tid; idx < 40*16; idx += 256) {
    int r = idx >> 4, e = idx & 15;
    relc[r][e] = rel[r*HE + e0 + e];
  }
  for (int m = tid; m < HM; m += 256) cnt[m] = 0.f;
  __syncthreads();

  for (int j = tid; j < HMT; j += 256) {
    int h = head[b*HMT+j], t = tail[b*HMT+j], r = rids[b*HMT+j];
    atomicAdd(&cnt[t], 1.f);
    atomicAdd(&cnt[h], 1.f);
    #pragma unroll
    for (int e = 0; e < 16; ++e) {
      float rv = relc[r][e];
      atomicAdd(&upd[t][e], cw[h][e] - rv);
      atomicAdd(&upd[h][e], cw[t][e] - rv);
    }
  }
  __syncthreads();

  for (int idx = tid; idx < HM*16; idx += 256) {
    int m = idx >> 4, e = idx & 15;
    float ic = 1.f / fmaxf(cnt[m], 1.f);
    u16* dst = An + ((long)b*HM + m) * (2*HE);
    dst[e0 + e]      = f2bf(cw[m][e]);
    dst[HE + e0 + e] = f2bf(upd[m][e] * ic);
  }
}

// ---- MFMA GEMM core: C[M,N] = act(A[M,K] @ B[N,K]^T) -----------------------
// 128x128 tile, BK=64, double-buffered LDS (2-phase pipeline: stage t+1 before
// compute t, ONE barrier per K-step), XOR-swizzled LDS (16B slot ^ row&7),
// 4 waves 2x2, 16x16x32 bf16 MFMA, global_load_lds staging.
template<int ACT, int OUTBF16, int BIG>
__device__ __forceinline__ void gemm_core(
    const u16* __restrict__ Ab, const u16* __restrict__ Bb,
    void* __restrict__ Cout, float* __restrict__ rowpart,
    int Mdim, int Ndim, int Kdim, int lda, int ldb, int ldc,
    int mtile, int ntile, u16* AsmB, u16* BsmB)
{
  const int m0 = mtile * 128;
  const int n0 = ntile * 128;
  const int tid = threadIdx.x;
  const int lane = tid & 63;
  const int wid = tid >> 6;
  const int wr = wid >> 1, wc = wid & 1;
  const int srw = lane >> 3;      // row within 8-row chunk
  const int sl  = lane & 7;       // 16B slot within 128B row

  f32x4 acc[4][4] = {};

  auto stage = [&](int buf, int k0) {
    u16* As = AsmB + buf*8192;
    u16* Bs = BsmB + buf*8192;
    #pragma unroll
    for (int i = 0; i < 4; ++i) {
      const int c = i*4 + wid;                 // chunk 0..15 (8 rows each)
      const int row = c*8 + srw;               // 0..127
      const int koff = k0 + ((sl ^ srw) * 8);  // inverse-swizzled source
      int ra = m0 + row; if (ra > Mdim-1) ra = Mdim-1;
      glds(Ab + (long)ra * lda + koff, &As[c*512]);
      int rn = n0 + row; if (rn > Ndim-1) rn = Ndim-1;
      glds(Bb + (long)rn * ldb + koff, &Bs[c*512]);
    }
  };

  const int NT = Kdim >> 6;
  stage(0, 0);
  __syncthreads();
  int cur = 0;
  for (int t = 0; t < NT; ++t) {
    if (t + 1 < NT) stage(cur ^ 1, (t + 1) << 6);
    const u16* As = AsmB + cur*8192;
    const u16* Bs = BsmB + cur*8192;
    #pragma unroll
    for (int kk = 0; kk < 2; ++kk) {
      bf16x8 af[4], bfr[4];
      #pragma unroll
      for (int mi = 0; mi < 4; ++mi) {
        const int R = wr*64 + mi*16 + (lane & 15);
        af[mi] = *(const bf16x8*)&As[R*64 + (((kk*4 + (lane>>4)) ^ (R & 7)) * 8)];
      }
      #pragma unroll
      for (int ni = 0; ni < 4; ++ni) {
        const int R = wc*64 + ni*16 + (lane & 15);
        bfr[ni] = *(const bf16x8*)&Bs[R*64 + (((kk*4 + (lane>>4)) ^ (R & 7)) * 8)];
      }
      #pragma unroll
      for (int mi = 0; mi < 4; ++mi)
        #pragma unroll
        for (int ni = 0; ni < 4; ++ni)
          acc[mi][ni] = __builtin_amdgcn_mfma_f32_16x16x32_bf16(af[mi], bfr[ni], acc[mi][ni], 0, 0, 0);
    }
    __syncthreads();   // drains vmcnt (stage t+1 landed) + protects buf reuse
    cur ^= 1;
  }

  const int cr0 = m0 + wr*64 + ((lane >> 4) * 4);
  const int cc0 = n0 + wc*64 + (lane & 15);

  if (BIG) {
    // store exp(logit) (bf16 padded / f32), accumulate row partials (atomic-free)
    float* rs = (float*)AsmB;
    #pragma unroll
    for (int mi = 0; mi < 4; ++mi) {
      #pragma unroll
      for (int r = 0; r < 4; ++r) {
        const int rowi = cr0 + mi*16 + r;
        float s = 0.f;
        #pragma unroll
        for (int ni = 0; ni < 4; ++ni) {
          const int col = cc0 + ni*16;
          if (col < Ndim) {
            float e = __expf(acc[mi][ni][r]);
            if (OUTBF16) ((u16*)Cout)[(long)rowi*ELD + col] = f2bf(e);
            else        ((float*)Cout)[(long)rowi*HV + col] = e;
            s += e;
          }
        }
        s += __shfl_xor(s, 8); s += __shfl_xor(s, 4);
        s += __shfl_xor(s, 2); s += __shfl_xor(s, 1);
        if ((lane & 15) == 0)
          rs[wc*128 + wr*64 + mi*16 + ((lane >> 4) << 2) + r] = s;
      }
    }
    __syncthreads();
    if (tid < 128)
      rowpart[(long)(m0 + tid) * NTILES + ntile] = rs[tid] + rs[128 + tid];
    return;
  }

  #pragma unroll
  for (int mi = 0; mi < 4; ++mi) {
    #pragma unroll
    for (int ni = 0; ni < 4; ++ni) {
      const int col = cc0 + ni*16;
      if (col < Ndim) {
        #pragma unroll
        for (int r = 0; r < 4; ++r) {
          const int rowi = cr0 + mi*16 + r;
          if (rowi < Mdim) {
            float v = acc[mi][ni][r];
            if (ACT == 1) v = fmaxf(v, 0.f);
            if (OUTBF16) ((u16*)Cout)[(long)rowi*ldc + col] = f2bf(v);
            else        ((float*)Cout)[(long)rowi*ldc + col] = v;
          }
        }
      }
    }
  }
}

// ---- plain / big GEMM wrappers ---------------------------------------------
template<int ACT, int OUTBF16, int BIG>
__global__ __launch_bounds__(256) void gemm_bt(
    const u16* __restrict__ A, const u16* __restrict__ Bm,
    void* __restrict__ Cout, float* __restrict__ rowpart,
    int Mdim, int Ndim, int Kdim, int lda, int ldb, int ldc,
    long Abs, long Bbs, long Cbs)
{
  __shared__ alignas(16) u16 Asm[2*8192];
  __shared__ alignas(16) u16 Bsm[2*8192];
  int mtile, ntile, bz;
  if (BIG) {
    const int wg = (blockIdx.x & 7) * NTILES + (blockIdx.x >> 3);
    mtile = wg & 7; ntile = wg >> 3; bz = 0;
  } else {
    mtile = blockIdx.x; ntile = blockIdx.y; bz = blockIdx.z;
  }
  const u16* Ab = A + (long)bz * Abs;
  const u16* Bb = Bm + (long)bz * Bbs;
  void* Cb = OUTBF16 ? (void*)((u16*)Cout + (long)bz * Cbs)
                     : (void*)((float*)Cout + (long)bz * Cbs);
  gemm_core<ACT,OUTBF16,BIG>(Ab, Bb, Cb, rowpart, Mdim, Ndim, Kdim,
                             lda, ldb, ldc, mtile, ntile, Asm, Bsm);
}

// composite small-GEMM launches.
// PHASE 0, grid (4,6,9):  z<8: node=relu(anode@wcat^T) batch z; z==8: relWr.
// PHASE 1, grid (4,6,24): z<8: relW2->P13[z][800..839]; z in 8..15: P1 batch
//                         z-8; z in 16..23: P3 batch z-16.
template<int PHASE>
__global__ __launch_bounds__(256) void gemm_multi(
    const u16* __restrict__ anode, const u16* __restrict__ wcat,
    u16* __restrict__ nodeb, const u16* __restrict__ rel_b,
    const u16* __restrict__ wr1, u16* __restrict__ relWr,
    const u16* __restrict__ wt_b, u16* __restrict__ P13)
{
  __shared__ alignas(16) u16 Asm[2*8192];
  __shared__ alignas(16) u16 Bsm[2*8192];
  const int mtile = blockIdx.x, ntile = blockIdx.y, z = blockIdx.z;
  if (PHASE == 0) {
    if (z < 8) {
      gemm_core<1,1,0>(anode + (long)z*HM*2*HE, wcat, nodeb + (long)z*HM*HE,
          nullptr, HM, HE, 2*HE, 2*HE, 2*HE, HE, mtile, ntile, Asm, Bsm);
    } else {
      if (mtile) return;
      gemm_core<0,1,0>(rel_b, wr1, relWr, nullptr,
          40, HE, HE, HE, HE, HE, 0, ntile, Asm, Bsm);
    }
  } else {
    if (z < 8) {
      if (mtile) return;
      gemm_core<0,1,0>(relWr, wt_b + HE, P13 + (long)z*840*HE + (long)800*HE,
          nullptr, 40, HE, HE, HE, 3*HE, HE, 0, ntile, Asm, Bsm);
    } else if (z < 16) {
      gemm_core<0,1,0>(nodeb + (long)(z-8)*HM*HE, wt_b,
          P13 + (long)(z-8)*840*HE, nullptr,
          HM, HE, HE, HE, 3*HE, HE, mtile, ntile, Asm, Bsm);
    } else {
      gemm_core<0,1,0>(nodeb + (long)(z-16)*HM*HE, wt_b + 2*HE,
          P13 + (long)(z-16)*840*HE + (long)HM*HE, nullptr,
          HM, HE, HE, HE, 3*HE, HE, mtile, ntile, Asm, Bsm);
    }
  }
}

// ---- multi-hop + gate: factored triple_prob, hops, softmax over M ----------
__global__ __launch_bounds__(256) void multihop_k(const float* __restrict__ scores,
    const float* __restrict__ hs, const float* __restrict__ gw,
    const float* __restrict__ gb,
    const int* __restrict__ head, const int* __restrict__ tail,
    const int* __restrict__ rids, const int* __restrict__ labels,
    const int* __restrict__ dist, float* __restrict__ gatev,
    float* __restrict__ cprob){
  const int bl = blockIdx.x;
  const int b = bl >> 7;
  const int tid = threadIdx.x;
  const int lane = tid & 63, wid = tid >> 6;
  __shared__ float srow[840];
  __shared__ float tp[HMT];
  __shared__ float ns[HM], sacc[HM], tot[HM], invc[HM], dec[HM];
  __shared__ float red[16];
  __shared__ float gred[4];
  const int* hb = head + b*HMT;
  const int* tb = tail + b*HMT;
  const int* rb = rids + b*HMT;
  const int* lb = labels + b*HMT;
  const float* sr = scores + (long)bl * 840;

  float gs = 0.f;
  for (int e = tid; e < HE; e += 256) gs += hs[(long)bl*HE + e] * gw[e];
  for (int o = 32; o; o >>= 1) gs += __shfl_down(gs, o);
  if (lane == 0) gred[wid] = gs;

  for (int i = tid; i < 840; i += 256) srow[i] = sr[i];
  for (int m = tid; m < HM; m += 256) {
    int d = dist[b*HM + m];
    float im = (d == 0) ? 1.f : 0.f;
    ns[m] = im; tot[m] = im * -100000.f;
    dec[m] = (d == 0) ? 1.f : ((d == 1) ? 0.8f : 0.64f);
    sacc[m] = 0.f; invc[m] = 0.f;
  }
  __syncthreads();
  if (tid == 0)
    gatev[bl] = 1.f / (1.f + __expf(-(gred[0]+gred[1]+gred[2]+gred[3] + gb[0])));
  for (int j = tid; j < HMT; j += 256) {
    atomicAdd(&invc[tb[j]], 1.f);
    float x = srow[hb[j]] + srow[400 + tb[j]] + srow[800 + rb[j]];
    tp[j] = (lb[j] == -1) ? 0.f : 1.f / (1.f + __expf(-x));
  }
  __syncthreads();
  for (int m = tid; m < HM; m += 256) invc[m] = 1.f / fmaxf(invc[m], 1.f);
  __syncthreads();

  for (int hop = 0; hop < 2; ++hop) {
    for (int j = tid; j < HMT; j += 256) {
      float u = ns[hb[j]] * 0.8f + tp[j];
      atomicAdd(&sacc[tb[j]], u);
    }
    __syncthreads();
    for (int m = tid; m < HM; m += 256) {
      float v = sacc[m] * invc[m];
      ns[m] = v; tot[m] += v * dec[m]; sacc[m] = 0.f;
    }
    __syncthreads();
  }

  float lmx = -3.4e38f;
  for (int m = tid; m < HM; m += 256) lmx = fmaxf(lmx, tot[m]);
  for (int o = 32; o; o >>= 1) lmx = fmaxf(lmx, __shfl_down(lmx, o));
  if (lane == 0) red[wid] = lmx;
  __syncthreads();
  float gmx = fmaxf(fmaxf(red[0], red[1]), fmaxf(red[2], red[3]));
  float ls = 0.f;
  for (int m = tid; m < HM; m += 256) ls += __expf(tot[m] - gmx);
  for (int o = 32; o; o >>= 1) ls += __shfl_down(ls, o);
  if (lane == 0) red[8 + wid] = ls;
  __syncthreads();
  float inv = 1.f / (red[8] + red[9] + red[10] + red[11]);
  float* outrow = cprob + (long)bl * HM;
  for (int m = tid; m < HM; m += 256) outrow[m] = __expf(tot[m] - gmx) * inv;
}

// ---- finalize: fused rowsum reduce + LDS-gather blend ----------------------
template<int EXPBF>
__global__ __launch_bounds__(256) void finalize_k(const void* __restrict__ expl,
    const float* __restrict__ rowpart, const float* __restrict__ gatev,
    const float* __restrict__ cprob, const int* __restrict__ vmm,
    float* __restrict__ out){
  const int r = blockIdx.x / 13;
  const int ch = blockIdx.x - r*13;
  const int tid = threadIdx.x;
  __shared__ float red[4];
  __shared__ float cpl[HM];
  float s = 0.f;
  for (int t = tid; t < NTILES; t += 256) s += rowpart[r*NTILES + t];
  for (int o = 32; o; o >>= 1) s += __shfl_down(s, o);
  if ((tid & 63) == 0) red[tid >> 6] = s;
  const float g = gatev[r];
  for (int m = tid; m < HM; m += 256) cpl[m] = g * cprob[r*HM + m];
  __syncthreads();
  const float scale = (1.f - g) / (red[0] + red[1] + red[2] + red[3]);
  const u16* erb = (const u16*)expl + (long)r * ELD;
  const float* erf = (const float*)expl + (long)r * HV;
  float* orow = out + (long)r * HV;
  #pragma unroll
  for (int it = 0; it < 2; ++it) {
    const int c = ch*4096 + it*2048 + tid*8;
    if (c + 8 <= HV) {
      float e[8];
      if (EXPBF) {
        bf16x8 v = *(const bf16x8*)&erb[c];
        #pragma unroll
        for (int i = 0; i < 8; ++i) e[i] = bf2f((u16)v[i]);
      } else {
        float4 a = *(const float4*)&erf[c];
        float4 b2 = *(const float4*)&erf[c+4];
        e[0]=a.x; e[1]=a.y; e[2]=a.z; e[3]=a.w;
        e[4]=b2.x; e[5]=b2.y; e[6]=b2.z; e[7]=b2.w;
      }
      int4 v0 = *(const int4*)&vmm[c];
      int4 v1 = *(const int4*)&vmm[c+4];
      const int ix[8] = {v0.x, v0.y, v0.z, v0.w, v1.x, v1.y, v1.z, v1.w};
      float o8[8];
      #pragma unroll
      for (int i = 0; i < 8; ++i)
        o8[i] = (ix[i] >= 0 ? cpl[ix[i]] : 0.f) + scale * e[i];
      *(float4*)&orow[c]   = make_float4(o8[0], o8[1], o8[2], o8[3]);
      *(float4*)&orow[c+4] = make_float4(o8[4], o8[5], o8[6], o8[7]);
    } else if (c < HV) {
      for (int i = 0; i < 8 && c + i < HV; ++i) {
        float e = EXPBF ? bf2f(((const u16*)expl)[(long)r*ELD + c + i]) : erf[c+i];
        int ix = vmm[c+i];
        orow[c+i] = (ix >= 0 ? cpl[ix] : 0.f) + scale * e;
      }
    }
  }
}

// ---------------------------------------------------------------------------
extern "C" void kernel_launch(void* const* d_in, const int* in_sizes, int n_in,
                              void* d_out, int out_size, void* d_ws, size_t ws_size,
                              hipStream_t stream)
{
  const float* hs   = (const float*)d_in[0];
  const float* wte  = (const float*)d_in[1];
  const float* rel  = (const float*)d_in[2];
  const float* Ws   = (const float*)d_in[3];
  const float* Wn   = (const float*)d_in[4];
  const float* Wr   = (const float*)d_in[5];
  const float* Wt   = (const float*)d_in[6];
  const float* gw   = (const float*)d_in[7];
  const float* gb   = (const float*)d_in[8];
  const int* cids   = (const int*)d_in[9];
  const int* rids   = (const int*)d_in[10];
  const int* head   = (const int*)d_in[11];
  const int* tail   = (const int*)d_in[12];
  const int* labels = (const int*)d_in[13];
  const int* dist   = (const int*)d_in[14];
  const int* vmap   = (const int*)d_in[15];
  const int* mmask  = (const int*)d_in[16];
  float* out = (float*)d_out;

  char* ws = (char*)d_ws;
  size_t o = 0;
  auto alloc = [&](size_t bytes) -> char* {
    char* p = ws + o; o = (o + bytes + 255) & ~(size_t)255; return p;
  };
  // fixed region (live across the whole call)
  u16* wte_b     = (u16*)alloc((size_t)HV*HE*2);        // 77.2 MB
  u16* hid_b     = (u16*)alloc((size_t)HBL*HE*2);       // 1.6 MB
  float* cprob   = (float*)alloc((size_t)HBL*HM*4);     // 1.6 MB
  float* rowpart = (float*)alloc((size_t)HBL*NTILES*4); // 1.6 MB
  float* gatev   = (float*)alloc(HBL*4);
  int* vmm       = (int*)alloc((size_t)HV*4);           // 0.2 MB

  // expl (bf16 exp of logits) aliases the mid-phase union region: every union
  // buffer is dead before the big GEMM writes expl (multihop runs first).
  const bool bigws = ws_size >= (size_t)196*1024*1024;
  u16* expl = (u16*)(ws + o);                           // 103.0 MB if bigws
  // union region (same offset as expl)
  u16* wcat  = (u16*)alloc((size_t)HE*2*HE*2);          // 2.4 MB
  u16* wr1   = (u16*)alloc((size_t)HE*HE*2);            // 1.2 MB
  u16* wt_b  = (u16*)alloc((size_t)HE*3*HE*2);          // 3.5 MB
  u16* rel_b = (u16*)alloc((size_t)40*HE*2);
  u16* anode = (u16*)alloc((size_t)HB*HM*2*HE*2);       // 9.8 MB
  u16* nodeb = (u16*)alloc((size_t)HB*HM*HE*2);         // 4.9 MB
  u16* relWr = (u16*)alloc((size_t)40*HE*2);
  float* scores = (float*)alloc((size_t)HB*HL*840*4);   // 3.4 MB
  u16* P13   = (u16*)alloc((size_t)HB*840*HE*2);        // 10.3 MB
  (void)in_sizes; (void)n_in; (void)out_size;

  // 1. fused preprocessing (incl. wte->bf16 and vmm packing)
  prep_k<<<5456 + 37693, 256, 0, stream>>>(hs, rel, Wr + (size_t)HE*HE, Wt,
      Ws + (size_t)HE*HE, Wn + (size_t)HE*HE, vmap, mmask, wte,
      hid_b, rel_b, wr1, wt_b, wcat, vmm, wte_b);

  // 2. fused GCN scatter -> anode (bf16 [8][400][1536])
  gcn_scatter_k<<<HB*48, 256, 0, stream>>>(wte, rel, cids, rids, head, tail, anode);

  // 3. composite: node = relu(anode @ wcat^T) x8  +  relWr = rel @ Wr1^T
  gemm_multi<0><<<dim3(4,6,9), 256, 0, stream>>>(anode, wcat, nodeb,
      rel_b, wr1, relWr, wt_b, P13);
  // 4. composite: relW2 broadcast x8 + P1 x8 + P3 x8 -> P13
  gemm_multi<1><<<dim3(4,6,24), 256, 0, stream>>>(anode, wcat, nodeb,
      rel_b, wr1, relWr, wt_b, P13);
  // 5. scores = hid @ P13^T: batched, M=128, N=840, K=768
  gemm_bt<0,0,0><<<dim3(1,7,8), 256, 0, stream>>>(hid_b, P13, scores,
      nullptr, HL, 840, HE, HE, HE, 840, (long)HL*HE, (long)840*HE, (long)HL*840);

  // 6. multi-hop + gate (consumes scores -> union region becomes dead)
  multihop_k<<<HBL, 256, 0, stream>>>(scores, hs, gw, gb, head, tail, rids,
      labels, dist, gatev, cprob);

  // 7. exp(hid @ wte^T) + rowsum partials. Grid 3144 = 8 XCDs x 393 n-tiles.
  if (bigws) {
    gemm_bt<0,1,1><<<3144, 256, 0, stream>>>(hid_b, wte_b, expl, rowpart,
        HBL, HV, HE, HE, HE, ELD, 0, 0, 0);
    finalize_k<1><<<HBL*13, 256, 0, stream>>>(expl, rowpart, gatev, cprob,
        vmm, out);
  } else {
    gemm_bt<0,0,1><<<3144, 256, 0, stream>>>(hid_b, wte_b, out, rowpart,
        HBL, HV, HE, HE, HE, HV, 0, 0, 0);
    finalize_k<0><<<HBL*13, 256, 0, stream>>>(out, rowpart, gatev, cprob,
        vmm, out);
  }
}

// Round 7
// 449.194 us; speedup vs baseline: 1.0864x; 1.0864x over previous
//
#include <hip/hip_runtime.h>
#include <stdint.h>

#define HB 8
#define HL 128
#define HV 50257
#define HE 768
#define HM 400
#define HMT 800
#define HBL (HB*HL)
#define NTILES 393   // ceil(HV/128)
#define ELD 50272    // padded bf16-exp leading dim (mult of 16)

typedef __attribute__((ext_vector_type(4))) float f32x4;
typedef __attribute__((ext_vector_type(8))) short bf16x8;
typedef unsigned short u16;

struct u16x4 { u16 x, y, z, w; };

__device__ __forceinline__ u16 f2bf(float x){
  union { float f; uint32_t u; } v; v.f = x;
  uint32_t r = v.u + 0x7fffu + ((v.u >> 16) & 1u);
  return (u16)(r >> 16);
}
__device__ __forceinline__ float bf2f(u16 b){
  union { uint32_t u; float f; } v; v.u = ((uint32_t)b) << 16;
  return v.f;
}
__device__ __forceinline__ void glds(const u16* g, const u16* l){
  __builtin_amdgcn_global_load_lds(
      (const __attribute__((address_space(1))) void*)g,
      (__attribute__((address_space(3))) void*)l, 16, 0, 0);
}

// ---- fused preprocessing: hid, rel, Wr1, Wt, wcat, vmm, wte cvt ------------
__global__ __launch_bounds__(256) void prep_k(const float* __restrict__ hs,
    const float* __restrict__ rel, const float* __restrict__ Wr1src,
    const float* __restrict__ Wtsrc, const float* __restrict__ Ws1,
    const float* __restrict__ Wn1, const int* __restrict__ vmap,
    const int* __restrict__ mmask, const float* __restrict__ wte,
    u16* __restrict__ hid_b, u16* __restrict__ rel_b,
    u16* __restrict__ wr1, u16* __restrict__ wt_b, u16* __restrict__ wcat,
    int* __restrict__ vmm, u16* __restrict__ wte_b){
  const int b = blockIdx.x, t = threadIdx.x;
  if (b >= 5456) {
    long i = (long)(b-5456)*256 + t;
    if (i < (long)HV*HE/4) {
      float4 x = ((const float4*)wte)[i];
      u16x4 y; y.x=f2bf(x.x); y.y=f2bf(x.y); y.z=f2bf(x.z); y.w=f2bf(x.w);
      ((u16x4*)wte_b)[i] = y;
    }
    return;
  }
  if (b < 768) {
    int i = b*256 + t;
    float4 x = ((const float4*)hs)[i];
    u16x4 y; y.x=f2bf(x.x); y.y=f2bf(x.y); y.z=f2bf(x.z); y.w=f2bf(x.w);
    ((u16x4*)hid_b)[i] = y;
  } else if (b < 798) {
    int i = (b-768)*256 + t;
    float4 x = ((const float4*)rel)[i];
    u16x4 y; y.x=f2bf(x.x); y.y=f2bf(x.y); y.z=f2bf(x.z); y.w=f2bf(x.w);
    ((u16x4*)rel_b)[i] = y;
  } else if (b < 1374) {
    int i = (b-798)*256 + t;
    float4 x = ((const float4*)Wr1src)[i];
    u16x4 y; y.x=f2bf(x.x); y.y=f2bf(x.y); y.z=f2bf(x.z); y.w=f2bf(x.w);
    ((u16x4*)wr1)[i] = y;
  } else if (b < 3102) {
    int i = (b-1374)*256 + t;
    float4 x = ((const float4*)Wtsrc)[i];
    u16x4 y; y.x=f2bf(x.x); y.y=f2bf(x.y); y.z=f2bf(x.z); y.w=f2bf(x.w);
    ((u16x4*)wt_b)[i] = y;
  } else if (b < 5406) {
    int i = (b-3102)*256 + t;
    int e = i / HE, k = i - e*HE;
    wcat[(long)e*(2*HE) + k]      = f2bf(Ws1[i]);
    wcat[(long)e*(2*HE) + HE + k] = f2bf(Wn1[i]);
  } else {
    int base = (b-5406)*1024 + t*4;
    #pragma unroll
    for (int i = 0; i < 4; ++i) {
      int c = base + i;
      if (c < HV) vmm[c] = mmask[c] ? vmap[c] : -1;
    }
  }
}

// ---- fused GCN scatter + anode build (per batch x 16-col chunk) ------------
__global__ __launch_bounds__(256) void gcn_scatter_k(const float* __restrict__ wte,
    const float* __restrict__ rel, const int* __restrict__ cids,
    const int* __restrict__ rids, const int* __restrict__ head,
    const int* __restrict__ tail, u16* __restrict__ An){
  const int ch = blockIdx.x % 48;
  const int b  = blockIdx.x / 48;
  const int e0 = ch * 16;
  __shared__ float cw[HM][17];
  __shared__ float upd[HM][17];
  __shared__ float relc[40][17];
  __shared__ float cnt[HM];
  const int tid = threadIdx.x;

  for (int idx = tid; idx < HM*16; idx += 256) {
    int m = idx >> 4, e = idx & 15;
    cw[m][e] = wte[(long)cids[b*HM+m]*HE + e0 + e];
    upd[m][e] = 0.f;
  }
  for (int idx = tid; idx < 40*16; idx += 256) {
    int r = idx >> 4, e = idx & 15;
    relc[r][e] = rel[r*HE + e0 + e];
  }
  for (int m = tid; m < HM; m += 256) cnt[m] = 0.f;
  __syncthreads();

  for (int j = tid; j < HMT; j += 256) {
    int h = head[b*HMT+j], t = tail[b*HMT+j], r = rids[b*HMT+j];
    atomicAdd(&cnt[t], 1.f);
    atomicAdd(&cnt[h], 1.f);
    #pragma unroll
    for (int e = 0; e < 16; ++e) {
      float rv = relc[r][e];
      atomicAdd(&upd[t][e], cw[h][e] - rv);
      atomicAdd(&upd[h][e], cw[t][e] - rv);
    }
  }
  __syncthreads();

  for (int idx = tid; idx < HM*16; idx += 256) {
    int m = idx >> 4, e = idx & 15;
    float ic = 1.f / fmaxf(cnt[m], 1.f);
    u16* dst = An + ((long)b*HM + m) * (2*HE);
    dst[e0 + e]      = f2bf(cw[m][e]);
    dst[HE + e0 + e] = f2bf(upd[m][e] * ic);
  }
}

// ---- MFMA GEMM core: C[M,N] = act(A[M,K] @ B[N,K]^T) -----------------------
// 128x128 tile, BK=64, XOR-swizzled LDS (16B slot ^ row&7), 4 waves 2x2,
// 16x16x32 bf16 MFMA, global_load_lds staging.
// DBUF=0: single buffer, stage/sync/compute/sync (occupancy-critical: 32KB LDS,
//         5 blocks/CU — wave-TLP hides latency). DBUF=1: double-buffered
//         prefetch (latency-critical small GEMMs at ~1 block/CU).
template<int ACT, int OUTBF16, int BIG, int DBUF>
__device__ __forceinline__ void gemm_core(
    const u16* __restrict__ Ab, const u16* __restrict__ Bb,
    void* __restrict__ Cout, float* __restrict__ rowpart,
    int Mdim, int Ndim, int Kdim, int lda, int ldb, int ldc,
    int mtile, int ntile, u16* AsmB, u16* BsmB)
{
  const int m0 = mtile * 128;
  const int n0 = ntile * 128;
  const int tid = threadIdx.x;
  const int lane = tid & 63;
  const int wid = tid >> 6;
  const int wr = wid >> 1, wc = wid & 1;
  const int srw = lane >> 3;      // row within 8-row chunk
  const int sl  = lane & 7;       // 16B slot within 128B row

  f32x4 acc[4][4] = {};

  auto stage = [&](int buf, int k0) {
    u16* As = AsmB + buf*8192;
    u16* Bs = BsmB + buf*8192;
    #pragma unroll
    for (int i = 0; i < 4; ++i) {
      const int c = i*4 + wid;                 // chunk 0..15 (8 rows each)
      const int row = c*8 + srw;               // 0..127
      const int koff = k0 + ((sl ^ srw) * 8);  // inverse-swizzled source
      int ra = m0 + row; if (ra > Mdim-1) ra = Mdim-1;
      glds(Ab + (long)ra * lda + koff, &As[c*512]);
      int rn = n0 + row; if (rn > Ndim-1) rn = Ndim-1;
      glds(Bb + (long)rn * ldb + koff, &Bs[c*512]);
    }
  };
  auto compute = [&](int buf) {
    const u16* As = AsmB + buf*8192;
    const u16* Bs = BsmB + buf*8192;
    #pragma unroll
    for (int kk = 0; kk < 2; ++kk) {
      bf16x8 af[4], bfr[4];
      #pragma unroll
      for (int mi = 0; mi < 4; ++mi) {
        const int R = wr*64 + mi*16 + (lane & 15);
        af[mi] = *(const bf16x8*)&As[R*64 + (((kk*4 + (lane>>4)) ^ (R & 7)) * 8)];
      }
      #pragma unroll
      for (int ni = 0; ni < 4; ++ni) {
        const int R = wc*64 + ni*16 + (lane & 15);
        bfr[ni] = *(const bf16x8*)&Bs[R*64 + (((kk*4 + (lane>>4)) ^ (R & 7)) * 8)];
      }
      #pragma unroll
      for (int mi = 0; mi < 4; ++mi)
        #pragma unroll
        for (int ni = 0; ni < 4; ++ni)
          acc[mi][ni] = __builtin_amdgcn_mfma_f32_16x16x32_bf16(af[mi], bfr[ni], acc[mi][ni], 0, 0, 0);
    }
  };

  const int NT = Kdim >> 6;
  if (DBUF) {
    stage(0, 0);
    __syncthreads();
    int cur = 0;
    for (int t = 0; t < NT; ++t) {
      if (t + 1 < NT) stage(cur ^ 1, (t + 1) << 6);
      compute(cur);
      __syncthreads();
      cur ^= 1;
    }
  } else {
    for (int t = 0; t < NT; ++t) {
      stage(0, t << 6);
      __syncthreads();
      compute(0);
      __syncthreads();
    }
  }

  const int cr0 = m0 + wr*64 + ((lane >> 4) * 4);
  const int cc0 = n0 + wc*64 + (lane & 15);

  if (BIG) {
    // store exp(logit) (bf16 padded / f32), accumulate row partials (atomic-free)
    float* rs = (float*)AsmB;
    #pragma unroll
    for (int mi = 0; mi < 4; ++mi) {
      #pragma unroll
      for (int r = 0; r < 4; ++r) {
        const int rowi = cr0 + mi*16 + r;
        float s = 0.f;
        #pragma unroll
        for (int ni = 0; ni < 4; ++ni) {
          const int col = cc0 + ni*16;
          if (col < Ndim) {
            float e = __expf(acc[mi][ni][r]);
            if (OUTBF16) ((u16*)Cout)[(long)rowi*ELD + col] = f2bf(e);
            else        ((float*)Cout)[(long)rowi*HV + col] = e;
            s += e;
          }
        }
        s += __shfl_xor(s, 8); s += __shfl_xor(s, 4);
        s += __shfl_xor(s, 2); s += __shfl_xor(s, 1);
        if ((lane & 15) == 0)
          rs[wc*128 + wr*64 + mi*16 + ((lane >> 4) << 2) + r] = s;
      }
    }
    __syncthreads();
    if (tid < 128)
      rowpart[(long)(m0 + tid) * NTILES + ntile] = rs[tid] + rs[128 + tid];
    return;
  }

  #pragma unroll
  for (int mi = 0; mi < 4; ++mi) {
    #pragma unroll
    for (int ni = 0; ni < 4; ++ni) {
      const int col = cc0 + ni*16;
      if (col < Ndim) {
        #pragma unroll
        for (int r = 0; r < 4; ++r) {
          const int rowi = cr0 + mi*16 + r;
          if (rowi < Mdim) {
            float v = acc[mi][ni][r];
            if (ACT == 1) v = fmaxf(v, 0.f);
            if (OUTBF16) ((u16*)Cout)[(long)rowi*ldc + col] = f2bf(v);
            else        ((float*)Cout)[(long)rowi*ldc + col] = v;
          }
        }
      }
    }
  }
}

// ---- plain / big GEMM wrappers ---------------------------------------------
template<int ACT, int OUTBF16, int BIG>
__global__ __launch_bounds__(256) void gemm_bt(
    const u16* __restrict__ A, const u16* __restrict__ Bm,
    void* __restrict__ Cout, float* __restrict__ rowpart,
    int Mdim, int Ndim, int Kdim, int lda, int ldb, int ldc,
    long Abs, long Bbs, long Cbs)
{
  // BIG: single 32KB buffer (occupancy); else double-buffered (latency).
  __shared__ alignas(16) u16 Asm[(BIG ? 1 : 2)*8192];
  __shared__ alignas(16) u16 Bsm[(BIG ? 1 : 2)*8192];
  int mtile, ntile, bz;
  if (BIG) {
    const int wg = (blockIdx.x & 7) * NTILES + (blockIdx.x >> 3);
    mtile = wg & 7; ntile = wg >> 3; bz = 0;
  } else {
    mtile = blockIdx.x; ntile = blockIdx.y; bz = blockIdx.z;
  }
  const u16* Ab = A + (long)bz * Abs;
  const u16* Bb = Bm + (long)bz * Bbs;
  void* Cb = OUTBF16 ? (void*)((u16*)Cout + (long)bz * Cbs)
                     : (void*)((float*)Cout + (long)bz * Cbs);
  gemm_core<ACT,OUTBF16,BIG,(BIG?0:1)>(Ab, Bb, Cb, rowpart, Mdim, Ndim, Kdim,
                                       lda, ldb, ldc, mtile, ntile, Asm, Bsm);
}

// composite small-GEMM launches (double-buffered core).
// PHASE 0, grid (4,6,9):  z<8: node=relu(anode@wcat^T) batch z; z==8: relWr.
// PHASE 1, grid (4,6,24): z<8: relW2->P13[z][800..839]; z in 8..15: P1 batch
//                         z-8; z in 16..23: P3 batch z-16.
template<int PHASE>
__global__ __launch_bounds__(256) void gemm_multi(
    const u16* __restrict__ anode, const u16* __restrict__ wcat,
    u16* __restrict__ nodeb, const u16* __restrict__ rel_b,
    const u16* __restrict__ wr1, u16* __restrict__ relWr,
    const u16* __restrict__ wt_b, u16* __restrict__ P13)
{
  __shared__ alignas(16) u16 Asm[2*8192];
  __shared__ alignas(16) u16 Bsm[2*8192];
  const int mtile = blockIdx.x, ntile = blockIdx.y, z = blockIdx.z;
  if (PHASE == 0) {
    if (z < 8) {
      gemm_core<1,1,0,1>(anode + (long)z*HM*2*HE, wcat, nodeb + (long)z*HM*HE,
          nullptr, HM, HE, 2*HE, 2*HE, 2*HE, HE, mtile, ntile, Asm, Bsm);
    } else {
      if (mtile) return;
      gemm_core<0,1,0,1>(rel_b, wr1, relWr, nullptr,
          40, HE, HE, HE, HE, HE, 0, ntile, Asm, Bsm);
    }
  } else {
    if (z < 8) {
      if (mtile) return;
      gemm_core<0,1,0,1>(relWr, wt_b + HE, P13 + (long)z*840*HE + (long)800*HE,
          nullptr, 40, HE, HE, HE, 3*HE, HE, 0, ntile, Asm, Bsm);
    } else if (z < 16) {
      gemm_core<0,1,0,1>(nodeb + (long)(z-8)*HM*HE, wt_b,
          P13 + (long)(z-8)*840*HE, nullptr,
          HM, HE, HE, HE, 3*HE, HE, mtile, ntile, Asm, Bsm);
    } else {
      gemm_core<0,1,0,1>(nodeb + (long)(z-16)*HM*HE, wt_b + 2*HE,
          P13 + (long)(z-16)*840*HE + (long)HM*HE, nullptr,
          HM, HE, HE, HE, 3*HE, HE, mtile, ntile, Asm, Bsm);
    }
  }
}

// ---- multi-hop + gate: factored triple_prob, hops, softmax over M ----------
__global__ __launch_bounds__(256) void multihop_k(const float* __restrict__ scores,
    const float* __restrict__ hs, const float* __restrict__ gw,
    const float* __restrict__ gb,
    const int* __restrict__ head, const int* __restrict__ tail,
    const int* __restrict__ rids, const int* __restrict__ labels,
    const int* __restrict__ dist, float* __restrict__ gatev,
    float* __restrict__ cprob){
  const int bl = blockIdx.x;
  const int b = bl >> 7;
  const int tid = threadIdx.x;
  const int lane = tid & 63, wid = tid >> 6;
  __shared__ float srow[840];
  __shared__ float tp[HMT];
  __shared__ float ns[HM], sacc[HM], tot[HM], invc[HM], dec[HM];
  __shared__ float red[16];
  __shared__ float gred[4];
  const int* hb = head + b*HMT;
  const int* tb = tail + b*HMT;
  const int* rb = rids + b*HMT;
  const int* lb = labels + b*HMT;
  const float* sr = scores + (long)bl * 840;

  float gs = 0.f;
  for (int e = tid; e < HE; e += 256) gs += hs[(long)bl*HE + e] * gw[e];
  for (int o = 32; o; o >>= 1) gs += __shfl_down(gs, o);
  if (lane == 0) gred[wid] = gs;

  for (int i = tid; i < 840; i += 256) srow[i] = sr[i];
  for (int m = tid; m < HM; m += 256) {
    int d = dist[b*HM + m];
    float im = (d == 0) ? 1.f : 0.f;
    ns[m] = im; tot[m] = im * -100000.f;
    dec[m] = (d == 0) ? 1.f : ((d == 1) ? 0.8f : 0.64f);
    sacc[m] = 0.f; invc[m] = 0.f;
  }
  __syncthreads();
  if (tid == 0)
    gatev[bl] = 1.f / (1.f + __expf(-(gred[0]+gred[1]+gred[2]+gred[3] + gb[0])));
  for (int j = tid; j < HMT; j += 256) {
    atomicAdd(&invc[tb[j]], 1.f);
    float x = srow[hb[j]] + srow[400 + tb[j]] + srow[800 + rb[j]];
    tp[j] = (lb[j] == -1) ? 0.f : 1.f / (1.f + __expf(-x));
  }
  __syncthreads();
  for (int m = tid; m < HM; m += 256) invc[m] = 1.f / fmaxf(invc[m], 1.f);
  __syncthreads();

  for (int hop = 0; hop < 2; ++hop) {
    for (int j = tid; j < HMT; j += 256) {
      float u = ns[hb[j]] * 0.8f + tp[j];
      atomicAdd(&sacc[tb[j]], u);
    }
    __syncthreads();
    for (int m = tid; m < HM; m += 256) {
      float v = sacc[m] * invc[m];
      ns[m] = v; tot[m] += v * dec[m]; sacc[m] = 0.f;
    }
    __syncthreads();
  }

  float lmx = -3.4e38f;
  for (int m = tid; m < HM; m += 256) lmx = fmaxf(lmx, tot[m]);
  for (int o = 32; o; o >>= 1) lmx = fmaxf(lmx, __shfl_down(lmx, o));
  if (lane == 0) red[wid] = lmx;
  __syncthreads();
  float gmx = fmaxf(fmaxf(red[0], red[1]), fmaxf(red[2], red[3]));
  float ls = 0.f;
  for (int m = tid; m < HM; m += 256) ls += __expf(tot[m] - gmx);
  for (int o = 32; o; o >>= 1) ls += __shfl_down(ls, o);
  if (lane == 0) red[8 + wid] = ls;
  __syncthreads();
  float inv = 1.f / (red[8] + red[9] + red[10] + red[11]);
  float* outrow = cprob + (long)bl * HM;
  for (int m = tid; m < HM; m += 256) outrow[m] = __expf(tot[m] - gmx) * inv;
}

// ---- finalize: fused rowsum reduce + LDS-gather blend ----------------------
template<int EXPBF>
__global__ __launch_bounds__(256) void finalize_k(const void* __restrict__ expl,
    const float* __restrict__ rowpart, const float* __restrict__ gatev,
    const float* __restrict__ cprob, const int* __restrict__ vmm,
    float* __restrict__ out){
  const int r = blockIdx.x / 13;
  const int ch = blockIdx.x - r*13;
  const int tid = threadIdx.x;
  __shared__ float red[4];
  __shared__ float cpl[HM];
  float s = 0.f;
  for (int t = tid; t < NTILES; t += 256) s += rowpart[r*NTILES + t];
  for (int o = 32; o; o >>= 1) s += __shfl_down(s, o);
  if ((tid & 63) == 0) red[tid >> 6] = s;
  const float g = gatev[r];
  for (int m = tid; m < HM; m += 256) cpl[m] = g * cprob[r*HM + m];
  __syncthreads();
  const float scale = (1.f - g) / (red[0] + red[1] + red[2] + red[3]);
  const u16* erb = (const u16*)expl + (long)r * ELD;
  const float* erf = (const float*)expl + (long)r * HV;
  float* orow = out + (long)r * HV;
  #pragma unroll
  for (int it = 0; it < 2; ++it) {
    const int c = ch*4096 + it*2048 + tid*8;
    if (c + 8 <= HV) {
      float e[8];
      if (EXPBF) {
        bf16x8 v = *(const bf16x8*)&erb[c];
        #pragma unroll
        for (int i = 0; i < 8; ++i) e[i] = bf2f((u16)v[i]);
      } else {
        float4 a = *(const float4*)&erf[c];
        float4 b2 = *(const float4*)&erf[c+4];
        e[0]=a.x; e[1]=a.y; e[2]=a.z; e[3]=a.w;
        e[4]=b2.x; e[5]=b2.y; e[6]=b2.z; e[7]=b2.w;
      }
      int4 v0 = *(const int4*)&vmm[c];
      int4 v1 = *(const int4*)&vmm[c+4];
      const int ix[8] = {v0.x, v0.y, v0.z, v0.w, v1.x, v1.y, v1.z, v1.w};
      float o8[8];
      #pragma unroll
      for (int i = 0; i < 8; ++i)
        o8[i] = (ix[i] >= 0 ? cpl[ix[i]] : 0.f) + scale * e[i];
      *(float4*)&orow[c]   = make_float4(o8[0], o8[1], o8[2], o8[3]);
      *(float4*)&orow[c+4] = make_float4(o8[4], o8[5], o8[6], o8[7]);
    } else if (c < HV) {
      for (int i = 0; i < 8 && c + i < HV; ++i) {
        float e = EXPBF ? bf2f(((const u16*)expl)[(long)r*ELD + c + i]) : erf[c+i];
        int ix = vmm[c+i];
        orow[c+i] = (ix >= 0 ? cpl[ix] : 0.f) + scale * e;
      }
    }
  }
}

// ---------------------------------------------------------------------------
extern "C" void kernel_launch(void* const* d_in, const int* in_sizes, int n_in,
                              void* d_out, int out_size, void* d_ws, size_t ws_size,
                              hipStream_t stream)
{
  const float* hs   = (const float*)d_in[0];
  const float* wte  = (const float*)d_in[1];
  const float* rel  = (const float*)d_in[2];
  const float* Ws   = (const float*)d_in[3];
  const float* Wn   = (const float*)d_in[4];
  const float* Wr   = (const float*)d_in[5];
  const float* Wt   = (const float*)d_in[6];
  const float* gw   = (const float*)d_in[7];
  const float* gb   = (const float*)d_in[8];
  const int* cids   = (const int*)d_in[9];
  const int* rids   = (const int*)d_in[10];
  const int* head   = (const int*)d_in[11];
  const int* tail   = (const int*)d_in[12];
  const int* labels = (const int*)d_in[13];
  const int* dist   = (const int*)d_in[14];
  const int* vmap   = (const int*)d_in[15];
  const int* mmask  = (const int*)d_in[16];
  float* out = (float*)d_out;

  char* ws = (char*)d_ws;
  size_t o = 0;
  auto alloc = [&](size_t bytes) -> char* {
    char* p = ws + o; o = (o + bytes + 255) & ~(size_t)255; return p;
  };
  // fixed region (live across the whole call)
  u16* wte_b     = (u16*)alloc((size_t)HV*HE*2);        // 77.2 MB
  u16* hid_b     = (u16*)alloc((size_t)HBL*HE*2);       // 1.6 MB
  float* cprob   = (float*)alloc((size_t)HBL*HM*4);     // 1.6 MB
  float* rowpart = (float*)alloc((size_t)HBL*NTILES*4); // 1.6 MB
  float* gatev   = (float*)alloc(HBL*4);
  int* vmm       = (int*)alloc((size_t)HV*4);           // 0.2 MB

  // expl (bf16 exp of logits) aliases the mid-phase union region: every union
  // buffer is dead before the big GEMM writes expl (multihop runs first).
  const bool bigws = ws_size >= (size_t)196*1024*1024;
  u16* expl = (u16*)(ws + o);                           // 103.0 MB if bigws
  // union region (same offset as expl)
  u16* wcat  = (u16*)alloc((size_t)HE*2*HE*2);          // 2.4 MB
  u16* wr1   = (u16*)alloc((size_t)HE*HE*2);            // 1.2 MB
  u16* wt_b  = (u16*)alloc((size_t)HE*3*HE*2);          // 3.5 MB
  u16* rel_b = (u16*)alloc((size_t)40*HE*2);
  u16* anode = (u16*)alloc((size_t)HB*HM*2*HE*2);       // 9.8 MB
  u16* nodeb = (u16*)alloc((size_t)HB*HM*HE*2);         // 4.9 MB
  u16* relWr = (u16*)alloc((size_t)40*HE*2);
  float* scores = (float*)alloc((size_t)HB*HL*840*4);   // 3.4 MB
  u16* P13   = (u16*)alloc((size_t)HB*840*HE*2);        // 10.3 MB
  (void)in_sizes; (void)n_in; (void)out_size;

  // 1. fused preprocessing (incl. wte->bf16 and vmm packing)
  prep_k<<<5456 + 37693, 256, 0, stream>>>(hs, rel, Wr + (size_t)HE*HE, Wt,
      Ws + (size_t)HE*HE, Wn + (size_t)HE*HE, vmap, mmask, wte,
      hid_b, rel_b, wr1, wt_b, wcat, vmm, wte_b);

  // 2. fused GCN scatter -> anode (bf16 [8][400][1536])
  gcn_scatter_k<<<HB*48, 256, 0, stream>>>(wte, rel, cids, rids, head, tail, anode);

  // 3. composite: node = relu(anode @ wcat^T) x8  +  relWr = rel @ Wr1^T
  gemm_multi<0><<<dim3(4,6,9), 256, 0, stream>>>(anode, wcat, nodeb,
      rel_b, wr1, relWr, wt_b, P13);
  // 4. composite: relW2 broadcast x8 + P1 x8 + P3 x8 -> P13
  gemm_multi<1><<<dim3(4,6,24), 256, 0, stream>>>(anode, wcat, nodeb,
      rel_b, wr1, relWr, wt_b, P13);
  // 5. scores = hid @ P13^T: batched, M=128, N=840, K=768
  gemm_bt<0,0,0><<<dim3(1,7,8), 256, 0, stream>>>(hid_b, P13, scores,
      nullptr, HL, 840, HE, HE, HE, 840, (long)HL*HE, (long)840*HE, (long)HL*840);

  // 6. multi-hop + gate (consumes scores -> union region becomes dead)
  multihop_k<<<HBL, 256, 0, stream>>>(scores, hs, gw, gb, head, tail, rids,
      labels, dist, gatev, cprob);

  // 7. exp(hid @ wte^T) + rowsum partials. Grid 3144 = 8 XCDs x 393 n-tiles.
  if (bigws) {
    gemm_bt<0,1,1><<<3144, 256, 0, stream>>>(hid_b, wte_b, expl, rowpart,
        HBL, HV, HE, HE, HE, ELD, 0, 0, 0);
    finalize_k<1><<<HBL*13, 256, 0, stream>>>(expl, rowpart, gatev, cprob,
        vmm, out);
  } else {
    gemm_bt<0,0,1><<<3144, 256, 0, stream>>>(hid_b, wte_b, out, rowpart,
        HBL, HV, HE, HE, HE, HV, 0, 0, 0);
    finalize_k<0><<<HBL*13, 256, 0, stream>>>(out, rowpart, gatev, cprob,
        vmm, out);
  }
}